// Round 1
// baseline (1584.816 us; speedup 1.0000x reference)
//
#include <hip/hip_runtime.h>
#include <math.h>

// Problem constants (fixed by setup_inputs)
#define BQ 512      // num queries
#define DIM 512     // feature dim
#define NMEM 131072 // num memory rows
#define TOPK 16

// Main-kernel tiling
#define BM 64            // query rows per block
#define BN 256           // memory rows per GEMM subtile
#define BKD 16           // k-depth per stage
#define CHUNK_N 1024     // memory rows per block (NSUB subtiles)
#define NSUB (CHUNK_N / BN)     // 4
#define CHUNKS (NMEM / CHUNK_N) // 128
#define BTILES (BQ / BM)        // 8
#define NEG_INF (-3.402823466e38f)

// ---------------------------------------------------------------------------
// 1/||q_b||  — one wave per row
__global__ __launch_bounds__(256) void qnorm_kernel(const float* __restrict__ q,
                                                    float* __restrict__ inv_qn) {
  int row = blockIdx.x * 4 + (threadIdx.x >> 6);
  int lane = threadIdx.x & 63;
  if (row >= BQ) return;
  const float4* r4 = (const float4*)(q + (size_t)row * DIM);
  float4 x0 = r4[lane * 2], x1 = r4[lane * 2 + 1];
  float ss = x0.x * x0.x + x0.y * x0.y + x0.z * x0.z + x0.w * x0.w +
             x1.x * x1.x + x1.y * x1.y + x1.z * x1.z + x1.w * x1.w;
  for (int off = 32; off; off >>= 1) ss += __shfl_down(ss, off);
  if (lane == 0) inv_qn[row] = 1.0f / sqrtf(ss);
}

// (1 + 0.3*imp[n]) / ||m_n||  — one wave per row
__global__ __launch_bounds__(256) void mscale_kernel(const float* __restrict__ mem,
                                                     const float* __restrict__ imp,
                                                     float* __restrict__ scale_n) {
  int row = blockIdx.x * 4 + (threadIdx.x >> 6);
  int lane = threadIdx.x & 63;
  if (row >= NMEM) return;
  const float4* r4 = (const float4*)(mem + (size_t)row * DIM);
  float4 x0 = r4[lane * 2], x1 = r4[lane * 2 + 1];
  float ss = x0.x * x0.x + x0.y * x0.y + x0.z * x0.z + x0.w * x0.w +
             x1.x * x1.x + x1.y * x1.y + x1.z * x1.z + x1.w * x1.w;
  for (int off = 32; off; off >>= 1) ss += __shfl_down(ss, off);
  if (lane == 0) scale_n[row] = (1.0f + 0.3f * imp[row]) / sqrtf(ss);
}

// ---------------------------------------------------------------------------
// Fused GEMM + per-row running top-16 over a CHUNK_N column range.
// Emits sorted 16-entry partial lists per (query row, chunk).
__global__ __launch_bounds__(256) void main_kernel(
    const float* __restrict__ query, const float* __restrict__ mem,
    const float* __restrict__ inv_qn, const float* __restrict__ scale_n,
    float* __restrict__ part_v, int* __restrict__ part_i) {
  __shared__ float As[BKD][BM];     // 4 KB  [k][m]
  __shared__ float Bs[BKD][BN];     // 16 KB [k][n]
  __shared__ float topv[BM][TOPK];  // 4 KB sorted desc
  __shared__ int   topi[BM][TOPK];  // 4 KB
  __shared__ float cbv[BM][32];     // 8 KB candidate buffer
  __shared__ int   cbi[BM][32];     // 8 KB
  __shared__ float cutoff[BM];
  __shared__ int   cnt[BM];
  __shared__ float qn_s[BM];

  const int tid = threadIdx.x;
  const int btile = blockIdx.x, chunk = blockIdx.y;
  const int bbase = btile * BM;
  const int nbase = chunk * CHUNK_N;
  const int rg = tid >> 5;  // 0..7  -> rows rg*8..rg*8+7
  const int cg = tid & 31;  // 0..31 -> cols cg*8..cg*8+7

  for (int e = tid; e < BM * TOPK; e += 256) {
    topv[e >> 4][e & 15] = NEG_INF;
    topi[e >> 4][e & 15] = -1;
  }
  if (tid < BM) {
    cutoff[tid] = NEG_INF;
    cnt[tid] = 0;
    qn_s[tid] = inv_qn[bbase + tid];
  }

  for (int sub = 0; sub < NSUB; ++sub) {
    const int n0 = nbase + sub * BN;
    float acc[8][8];
#pragma unroll
    for (int i = 0; i < 8; ++i)
#pragma unroll
      for (int j = 0; j < 8; ++j) acc[i][j] = 0.0f;

    for (int kt = 0; kt < DIM / BKD; ++kt) {
      const int k0 = kt * BKD;
      {  // stage A (transpose to [k][m])
        int ar = tid >> 2, ak = (tid & 3) << 2;
        const float4 av = *(const float4*)(query + (size_t)(bbase + ar) * DIM + k0 + ak);
        As[ak][ar] = av.x; As[ak + 1][ar] = av.y;
        As[ak + 2][ar] = av.z; As[ak + 3][ar] = av.w;
      }
      {  // stage B (transpose to [k][n])
        int bk = (tid & 3) << 2, r0 = tid >> 2;
#pragma unroll
        for (int q4 = 0; q4 < 4; ++q4) {
          int br = q4 * 64 + r0;
          const float4 bv = *(const float4*)(mem + (size_t)(n0 + br) * DIM + k0 + bk);
          Bs[bk][br] = bv.x; Bs[bk + 1][br] = bv.y;
          Bs[bk + 2][br] = bv.z; Bs[bk + 3][br] = bv.w;
        }
      }
      __syncthreads();
#pragma unroll
      for (int kk = 0; kk < BKD; ++kk) {
        float a[8], bb[8];
        *(float4*)&a[0] = *(const float4*)&As[kk][rg * 8];
        *(float4*)&a[4] = *(const float4*)&As[kk][rg * 8 + 4];
        *(float4*)&bb[0] = *(const float4*)&Bs[kk][cg * 8];
        *(float4*)&bb[4] = *(const float4*)&Bs[kk][cg * 8 + 4];
#pragma unroll
        for (int i = 0; i < 8; ++i)
#pragma unroll
          for (int j = 0; j < 8; ++j) acc[i][j] += a[i] * bb[j];
      }
      __syncthreads();
    }

    // scale: boosted = dot * (1/|q|) * ((1+0.3 imp)/|m|)
    float sc[8], qs[8];
    *(float4*)&sc[0] = *(const float4*)(scale_n + n0 + cg * 8);
    *(float4*)&sc[4] = *(const float4*)(scale_n + n0 + cg * 8 + 4);
#pragma unroll
    for (int i = 0; i < 8; ++i) qs[i] = qn_s[rg * 8 + i];
#pragma unroll
    for (int i = 0; i < 8; ++i)
#pragma unroll
      for (int j = 0; j < 8; ++j) acc[i][j] *= qs[i] * sc[j];

    // filter + merge, one column-pass at a time (<=32 candidates/row/pass)
    const int cb = n0 + cg * 8;
#pragma unroll
    for (int p = 0; p < 8; ++p) {
#pragma unroll
      for (int i = 0; i < 8; ++i) {
        int r = rg * 8 + i;
        float v = acc[i][p];
        if (v > cutoff[r]) {
          int pos = atomicAdd(&cnt[r], 1);
          if (pos < 32) { cbv[r][pos] = v; cbi[r][pos] = cb + p; }
        }
      }
      __syncthreads();
      if (tid < BM) {
        int r = tid, m = cnt[r];
        if (m > 32) m = 32;
        for (int c = 0; c < m; ++c) {
          float v = cbv[r][c];
          int id = cbi[r][c];
          if (v > topv[r][TOPK - 1]) {
            int j = TOPK - 1;
            while (j > 0 && topv[r][j - 1] < v) {
              topv[r][j] = topv[r][j - 1];
              topi[r][j] = topi[r][j - 1];
              --j;
            }
            topv[r][j] = v;
            topi[r][j] = id;
          }
        }
        cnt[r] = 0;
        cutoff[r] = topv[r][TOPK - 1];
      }
      __syncthreads();
    }
  }

  // write partials: layout [b][chunk][16]
  for (int e = tid; e < BM * TOPK; e += 256) {
    int r = e >> 4, j = e & 15;
    size_t o = ((size_t)(bbase + r) * CHUNKS + chunk) * TOPK + j;
    part_v[o] = topv[r][j];
    part_i[o] = topi[r][j];
  }
}

// ---------------------------------------------------------------------------
// Per query: merge CHUNKS*16 partials -> sorted top-16, write vals + gather.
#define CAND (CHUNKS * TOPK)  // 2048
__global__ __launch_bounds__(256) void final_kernel(
    const float* __restrict__ part_v, const int* __restrict__ part_i,
    const float* __restrict__ mem, float* __restrict__ out) {
  __shared__ float cv[CAND];
  __shared__ int ci[CAND];
  __shared__ float rv[256];
  __shared__ int rp[256];
  __shared__ float outv[TOPK];
  __shared__ int outi[TOPK];
  const int b = blockIdx.x, tid = threadIdx.x;
  const size_t base = (size_t)b * CAND;
  for (int e = tid; e < CAND; e += 256) { cv[e] = part_v[base + e]; ci[e] = part_i[base + e]; }
  __syncthreads();
  for (int j = 0; j < TOPK; ++j) {
    float best = NEG_INF;
    int bp = 0;
    for (int e = tid; e < CAND; e += 256)
      if (cv[e] > best) { best = cv[e]; bp = e; }
    rv[tid] = best;
    rp[tid] = bp;
    __syncthreads();
    for (int s = 128; s; s >>= 1) {
      if (tid < s) {
        if (rv[tid + s] > rv[tid] ||
            (rv[tid + s] == rv[tid] && rp[tid + s] < rp[tid])) {
          rv[tid] = rv[tid + s];
          rp[tid] = rp[tid + s];
        }
      }
      __syncthreads();
    }
    if (tid == 0) {
      outv[j] = rv[0];
      outi[j] = ci[rp[0]];
      cv[rp[0]] = NEG_INF;
    }
    __syncthreads();
  }
  if (tid < TOPK) out[(size_t)b * TOPK + tid] = outv[tid];
  // gather 16 rows of 512 floats = 2048 float4
  for (int e = tid; e < TOPK * (DIM / 4); e += 256) {
    int j = e >> 7, t = e & 127;
    int idx = outi[j];
    const float4* src = (const float4*)(mem + (size_t)idx * DIM);
    float4* dst = (float4*)(out + BQ * TOPK + ((size_t)(b * TOPK + j)) * DIM);
    dst[t] = src[t];
  }
}

// ---------------------------------------------------------------------------
extern "C" void kernel_launch(void* const* d_in, const int* in_sizes, int n_in,
                              void* d_out, int out_size, void* d_ws, size_t ws_size,
                              hipStream_t stream) {
  const float* query = (const float*)d_in[0];
  const float* mem = (const float*)d_in[1];
  const float* imp = (const float*)d_in[2];
  float* out = (float*)d_out;

  // ws layout (floats): inv_qn[512] | scale_n[131072] | part_v[512*128*16] | part_i (int)
  float* ws = (float*)d_ws;
  float* inv_qn = ws;
  float* scale_n = ws + BQ;
  float* part_v = scale_n + NMEM;
  int* part_i = (int*)(part_v + (size_t)BQ * CHUNKS * TOPK);

  hipLaunchKernelGGL(qnorm_kernel, dim3(BQ / 4), dim3(256), 0, stream, query, inv_qn);
  hipLaunchKernelGGL(mscale_kernel, dim3(NMEM / 4), dim3(256), 0, stream, mem, imp, scale_n);
  hipLaunchKernelGGL(main_kernel, dim3(BTILES, CHUNKS), dim3(256), 0, stream,
                     query, mem, inv_qn, scale_n, part_v, part_i);
  hipLaunchKernelGGL(final_kernel, dim3(BQ), dim3(256), 0, stream,
                     part_v, part_i, mem, out);
}

// Round 2
// 816.687 us; speedup vs baseline: 1.9405x; 1.9405x over previous
//
#include <hip/hip_runtime.h>
#include <hip/hip_bf16.h>
#include <math.h>

// Problem constants
#define BQ 512
#define DIM 512
#define NMEM 131072
#define TOPK 16

// Tiling
#define BM 128                   // query rows per block
#define BN 128                   // memory rows per subtile
#define BK 32                    // k per stage (one MFMA-K)
#define NSUB 8
#define CHUNK_N (BN * NSUB)      // 1024 memory rows per block
#define CHUNKS (NMEM / CHUNK_N)  // 128
#define BTILES (BQ / BM)         // 4
#define CAP 32                   // candidate buffer per row
#define RESCORE 32               // global candidates rescored in fp32
#define LDSTR 40                 // LDS row stride in ushorts (80 B, conflict-free)
#define NEG_INF (-3.402823466e38f)

typedef unsigned short u16;
typedef unsigned int u32;
typedef short bf16x8 __attribute__((ext_vector_type(8)));
typedef float f32x4 __attribute__((ext_vector_type(4)));

static __device__ inline u32 pack2(float a, float b) {
  __hip_bfloat162 p = __float22bfloat162_rn(make_float2(a, b));
  return *(u32*)&p;
}

// ---------------------------------------------------------------------------
// prep: inv_qn[b] = 1/||q_b|| (fp32 exact) + query converted to bf16
__global__ __launch_bounds__(256) void prep_kernel(const float* __restrict__ q,
                                                   float* __restrict__ inv_qn,
                                                   u16* __restrict__ qb) {
  int row = blockIdx.x * 4 + (threadIdx.x >> 6);
  int lane = threadIdx.x & 63;
  const float4* r4 = (const float4*)(q + (size_t)row * DIM);
  float4 x0 = r4[lane * 2], x1 = r4[lane * 2 + 1];
  float ss = x0.x * x0.x + x0.y * x0.y + x0.z * x0.z + x0.w * x0.w +
             x1.x * x1.x + x1.y * x1.y + x1.z * x1.z + x1.w * x1.w;
#pragma unroll
  for (int off = 32; off; off >>= 1) ss += __shfl_down(ss, off);
  if (lane == 0) inv_qn[row] = 1.0f / sqrtf(ss);
  uint4 w;
  w.x = pack2(x0.x, x0.y);
  w.y = pack2(x0.z, x0.w);
  w.z = pack2(x1.x, x1.y);
  w.w = pack2(x1.z, x1.w);
  *(uint4*)(qb + (size_t)row * DIM + lane * 8) = w;
}

// ---------------------------------------------------------------------------
// main: bf16 MFMA scoring + fused per-row running top-16 per chunk.
__global__ __launch_bounds__(256, 2) void main_kernel(
    const u16* __restrict__ qb, const float* __restrict__ mem,
    const float* __restrict__ imp, const float* __restrict__ inv_qn,
    float* __restrict__ part_v, int* __restrict__ part_i) {
  __shared__ __align__(16) u16 As[BM * LDSTR];  // 10240 B
  __shared__ __align__(16) u16 Bs[BN * LDSTR];  // 10240 B
  __shared__ float topv[BM][TOPK];
  __shared__ int topi[BM][TOPK];
  __shared__ float cbv[BM * CAP];
  __shared__ int cbi[BM * CAP];
  __shared__ float cutoff[BM];
  __shared__ int cnt[BM];
  __shared__ float qn_s[BM];
  __shared__ float msum[BM * 4];
  __shared__ float colscale[BN];
  __shared__ int again;

  const int tid = threadIdx.x;
  const int lane = tid & 63, wid = tid >> 6;
  const int wm = wid >> 1, wn = wid & 1;
  const int c16 = lane & 15, quad = lane >> 4;

  // XCD swizzle: 4 blocks sharing a chunk land on the same XCD (lin % 8)
  const int lin = blockIdx.x;
  const int btile = (lin >> 3) & 3;
  const int chunk = (lin & 7) + ((lin >> 5) << 3);
  const int bbase = btile * BM;

  for (int e = tid; e < BM * TOPK; e += 256) {
    topv[e >> 4][e & 15] = NEG_INF;
    topi[e >> 4][e & 15] = -1;
  }
  if (tid < BM) {
    cutoff[tid] = NEG_INF;
    cnt[tid] = 0;
    qn_s[tid] = inv_qn[bbase + tid];
  }
  if (tid == 0) again = 0;
  __syncthreads();

  float qnl[16];
#pragma unroll
  for (int ii = 0; ii < 16; ++ii)
    qnl[ii] = qn_s[wm * 64 + (ii >> 2) * 16 + quad * 4 + (ii & 3)];

  // staging assignments: thread covers rows (tid>>2) and (tid>>2)+64, k-chunk tid&3
  const int arow = tid >> 2, akc = tid & 3;
  const u16* qsrc0 = qb + (size_t)(bbase + arow) * DIM + akc * 8;
  const u16* qsrc1 = qsrc0 + (size_t)64 * DIM;
  u16* adst0 = As + arow * LDSTR + akc * 8;
  u16* adst1 = adst0 + 64 * LDSTR;
  u16* bdst0 = Bs + arow * LDSTR + akc * 8;
  u16* bdst1 = bdst0 + 64 * LDSTR;

  for (int sub = 0; sub < NSUB; ++sub) {
    const int n0g = chunk * CHUNK_N + sub * BN;
    const float* bsrc0 = mem + (size_t)(n0g + arow) * DIM + akc * 8;
    const float* bsrc1 = bsrc0 + (size_t)64 * DIM;

    f32x4 acc[4][4];
#pragma unroll
    for (int mi = 0; mi < 4; ++mi)
#pragma unroll
      for (int ni = 0; ni < 4; ++ni) acc[mi][ni] = (f32x4){0.f, 0.f, 0.f, 0.f};
    float ss0 = 0.f, ss1 = 0.f;

    for (int kt = 0; kt < DIM / BK; ++kt) {
      const int k0 = kt * BK;
      uint4 qa0 = *(const uint4*)(qsrc0 + k0);
      uint4 qa1 = *(const uint4*)(qsrc1 + k0);
      float4 b0a = *(const float4*)(bsrc0 + k0);
      float4 b0b = *(const float4*)(bsrc0 + k0 + 4);
      float4 b1a = *(const float4*)(bsrc1 + k0);
      float4 b1b = *(const float4*)(bsrc1 + k0 + 4);
      ss0 += b0a.x * b0a.x + b0a.y * b0a.y + b0a.z * b0a.z + b0a.w * b0a.w +
             b0b.x * b0b.x + b0b.y * b0b.y + b0b.z * b0b.z + b0b.w * b0b.w;
      ss1 += b1a.x * b1a.x + b1a.y * b1a.y + b1a.z * b1a.z + b1a.w * b1a.w +
             b1b.x * b1b.x + b1b.y * b1b.y + b1b.z * b1b.z + b1b.w * b1b.w;
      __syncthreads();  // previous iter's frag reads complete
      *(uint4*)adst0 = qa0;
      *(uint4*)adst1 = qa1;
      uint4 w0, w1;
      w0.x = pack2(b0a.x, b0a.y); w0.y = pack2(b0a.z, b0a.w);
      w0.z = pack2(b0b.x, b0b.y); w0.w = pack2(b0b.z, b0b.w);
      w1.x = pack2(b1a.x, b1a.y); w1.y = pack2(b1a.z, b1a.w);
      w1.z = pack2(b1b.x, b1b.y); w1.w = pack2(b1b.z, b1b.w);
      *(uint4*)bdst0 = w0;
      *(uint4*)bdst1 = w1;
      __syncthreads();
      bf16x8 af[4], bfr[4];
#pragma unroll
      for (int mi = 0; mi < 4; ++mi)
        af[mi] = *(const bf16x8*)&As[(wm * 64 + mi * 16 + c16) * LDSTR + quad * 8];
#pragma unroll
      for (int ni = 0; ni < 4; ++ni)
        bfr[ni] = *(const bf16x8*)&Bs[(wn * 64 + ni * 16 + c16) * LDSTR + quad * 8];
#pragma unroll
      for (int mi = 0; mi < 4; ++mi)
#pragma unroll
        for (int ni = 0; ni < 4; ++ni)
          acc[mi][ni] = __builtin_amdgcn_mfma_f32_16x16x32_bf16(
              af[mi], bfr[ni], acc[mi][ni], 0, 0, 0);
    }

    // column norms (from exact fp32 staged values) -> colscale
    msum[arow * 4 + akc] = ss0;
    msum[(arow + 64) * 4 + akc] = ss1;
    __syncthreads();
    if (tid < BN)
      colscale[tid] = (1.0f + 0.3f * imp[n0g + tid]) /
                      sqrtf(msum[tid * 4] + msum[tid * 4 + 1] +
                            msum[tid * 4 + 2] + msum[tid * 4 + 3]);
    __syncthreads();

    float scl[4];
    int gcol[4];
#pragma unroll
    for (int ni = 0; ni < 4; ++ni) {
      scl[ni] = colscale[wn * 64 + ni * 16 + c16];
      gcol[ni] = n0g + wn * 64 + ni * 16 + c16;
    }
#pragma unroll
    for (int mi = 0; mi < 4; ++mi)
#pragma unroll
      for (int ni = 0; ni < 4; ++ni)
#pragma unroll
        for (int reg = 0; reg < 4; ++reg)
          acc[mi][ni][reg] *= qnl[mi * 4 + reg] * scl[ni];

    // push/merge retry loop (consumed-bit dedup)
    unsigned long long consumed = 0ull;
    for (;;) {
      float cutl[16];
#pragma unroll
      for (int ii = 0; ii < 16; ++ii)
        cutl[ii] = cutoff[wm * 64 + (ii >> 2) * 16 + quad * 4 + (ii & 3)];
#pragma unroll
      for (int mi = 0; mi < 4; ++mi)
#pragma unroll
        for (int reg = 0; reg < 4; ++reg) {
          const int r = wm * 64 + mi * 16 + quad * 4 + reg;
          const float cl = cutl[mi * 4 + reg];
#pragma unroll
          for (int ni = 0; ni < 4; ++ni) {
            const int bit = mi * 16 + ni * 4 + reg;
            const float v = acc[mi][ni][reg];
            if (!((consumed >> bit) & 1ull) && v > cl) {
              int pos = atomicAdd(&cnt[r], 1);
              if (pos < CAP) {
                cbv[r * CAP + pos] = v;
                cbi[r * CAP + pos] = gcol[ni];
                consumed |= 1ull << bit;
              }
            }
          }
        }
      __syncthreads();
      if (tid < BM) {
        const int r = tid;
        const int m = cnt[r];
        const int take = m < CAP ? m : CAP;
        for (int c = 0; c < take; ++c) {
          const float v = cbv[r * CAP + c];
          const int id = cbi[r * CAP + c];
          if (v > topv[r][TOPK - 1]) {
            int j = TOPK - 1;
            while (j > 0 && topv[r][j - 1] < v) {
              topv[r][j] = topv[r][j - 1];
              topi[r][j] = topi[r][j - 1];
              --j;
            }
            topv[r][j] = v;
            topi[r][j] = id;
          }
        }
        cutoff[r] = topv[r][TOPK - 1];
        if (m > CAP) again = 1;
        cnt[r] = 0;
      }
      __syncthreads();
      const int more = again;
      __syncthreads();
      if (tid == 0) again = 0;
      if (!more) break;
    }
  }

  for (int e = tid; e < BM * TOPK; e += 256) {
    const int r = e >> 4, j = e & 15;
    const size_t o = ((size_t)(bbase + r) * CHUNKS + chunk) * TOPK + j;
    part_v[o] = topv[r][j];
    part_i[o] = topi[r][j];
  }
}

// ---------------------------------------------------------------------------
// final: merge partials -> top-32 approx -> exact fp32 rescore -> top-16 + gather
#define CAND (CHUNKS * TOPK)  // 2048
__global__ __launch_bounds__(256) void final_kernel(
    const float* __restrict__ part_v, const int* __restrict__ part_i,
    const float* __restrict__ mem, const float* __restrict__ query,
    const float* __restrict__ imp, const float* __restrict__ inv_qn,
    float* __restrict__ out) {
  __shared__ float cv[CAND];
  __shared__ int ci[CAND];
  __shared__ float q_s[DIM];
  __shared__ float rv[4];
  __shared__ int rp[4];
  __shared__ float exv[RESCORE];
  __shared__ int exi[RESCORE];
  __shared__ float selv[TOPK];
  __shared__ int seli[TOPK];
  const int b = blockIdx.x, tid = threadIdx.x;
  const int lane = tid & 63, wid = tid >> 6;
  const size_t base = (size_t)b * CAND;
  for (int e = tid; e < CAND; e += 256) {
    cv[e] = part_v[base + e];
    ci[e] = part_i[base + e];
  }
  q_s[tid] = query[(size_t)b * DIM + tid];
  q_s[tid + 256] = query[(size_t)b * DIM + 256 + tid];
  __syncthreads();

  // top-RESCORE approx candidates
  for (int j = 0; j < RESCORE; ++j) {
    float best = NEG_INF;
    int bp = 0;
    for (int e = tid; e < CAND; e += 256)
      if (cv[e] > best) { best = cv[e]; bp = e; }
#pragma unroll
    for (int off = 32; off; off >>= 1) {
      float ov = __shfl_down(best, off);
      int op = __shfl_down(bp, off);
      if (ov > best) { best = ov; bp = op; }
    }
    if (lane == 0) { rv[wid] = best; rp[wid] = bp; }
    __syncthreads();
    if (tid == 0) {
      float bb = rv[0];
      int pp = rp[0];
      for (int w = 1; w < 4; ++w)
        if (rv[w] > bb) { bb = rv[w]; pp = rp[w]; }
      exi[j] = ci[pp];
      cv[pp] = NEG_INF;
    }
    __syncthreads();
  }

  // exact fp32 rescore: one wave per candidate
  const float iq = inv_qn[b];
  for (int jj = wid; jj < RESCORE; jj += 4) {
    const int idx = exi[jj];
    const float4* mr = (const float4*)(mem + (size_t)idx * DIM);
    float4 m0 = mr[lane * 2], m1 = mr[lane * 2 + 1];
    float4 q0 = *(const float4*)&q_s[lane * 8];
    float4 q1 = *(const float4*)&q_s[lane * 8 + 4];
    float dt = m0.x * q0.x + m0.y * q0.y + m0.z * q0.z + m0.w * q0.w +
               m1.x * q1.x + m1.y * q1.y + m1.z * q1.z + m1.w * q1.w;
    float mm = m0.x * m0.x + m0.y * m0.y + m0.z * m0.z + m0.w * m0.w +
               m1.x * m1.x + m1.y * m1.y + m1.z * m1.z + m1.w * m1.w;
#pragma unroll
    for (int off = 32; off; off >>= 1) {
      dt += __shfl_down(dt, off);
      mm += __shfl_down(mm, off);
    }
    if (lane == 0)
      exv[jj] = dt * iq * (1.0f + 0.3f * imp[idx]) / sqrtf(mm);
  }
  __syncthreads();

  // exact top-16 of 32 (tie-break: smaller index, matching lax.top_k)
  if (tid == 0) {
    u32 used = 0;
    for (int j = 0; j < TOPK; ++j) {
      float bb = NEG_INF;
      int pp = -1;
      for (int c = 0; c < RESCORE; ++c) {
        if ((used >> c) & 1u) continue;
        const float v = exv[c];
        if (v > bb || (pp >= 0 && v == bb && exi[c] < exi[pp])) { bb = v; pp = c; }
      }
      used |= 1u << pp;
      selv[j] = bb;
      seli[j] = exi[pp];
    }
  }
  __syncthreads();
  if (tid < TOPK) out[(size_t)b * TOPK + tid] = selv[tid];
  for (int e = tid; e < TOPK * (DIM / 4); e += 256) {
    const int j = e >> 7, t = e & 127;
    const float4* src = (const float4*)(mem + (size_t)seli[j] * DIM);
    float4* dst = (float4*)(out + (size_t)BQ * TOPK + ((size_t)b * TOPK + j) * DIM);
    dst[t] = src[t];
  }
}

// ---------------------------------------------------------------------------
extern "C" void kernel_launch(void* const* d_in, const int* in_sizes, int n_in,
                              void* d_out, int out_size, void* d_ws, size_t ws_size,
                              hipStream_t stream) {
  const float* query = (const float*)d_in[0];
  const float* mem = (const float*)d_in[1];
  const float* imp = (const float*)d_in[2];
  float* out = (float*)d_out;

  // ws: inv_qn[512] f32 | qb[512*512] bf16 | part_v[512*128*16] f32 | part_i
  float* ws = (float*)d_ws;
  float* inv_qn = ws;
  u16* qb = (u16*)(ws + BQ);
  float* part_v = (float*)((char*)qb + (size_t)BQ * DIM * 2);
  int* part_i = (int*)(part_v + (size_t)BQ * CHUNKS * TOPK);

  hipLaunchKernelGGL(prep_kernel, dim3(BQ / 4), dim3(256), 0, stream,
                     query, inv_qn, qb);
  hipLaunchKernelGGL(main_kernel, dim3(BTILES * CHUNKS), dim3(256), 0, stream,
                     qb, mem, imp, inv_qn, part_v, part_i);
  hipLaunchKernelGGL(final_kernel, dim3(BQ), dim3(256), 0, stream,
                     part_v, part_i, mem, query, imp, inv_qn, out);
}